// Round 14
// baseline (647.540 us; speedup 1.0000x reference)
//
#include <hip/hip_runtime.h>
#include <hip/hip_fp16.h>

#define NN 200000
#define NE 4000000

// ---- binned CSR build params ----
constexpr int BSH = 9;
constexpr int BW = 1 << BSH;                  // 512
constexpr int NB2 = (NN + BW - 1) / BW;       // 391
constexpr int NWG1 = 512;
constexpr int CH = (NE + NWG1 - 1) / NWG1;    // 7813
constexpr int CAP = 12288;
constexpr int SPLIT = 100000;                 // src-range blocking: 100K x 32B = 3.2MB/pass
static_assert(NWG1 == 512, "shifts below assume 512");

__device__ __forceinline__ float softplus_f(float x) {
    return fmaxf(x, 0.0f) + log1pf(expf(-fabsf(x)));
}

// ---------------- binned CSR build (unchanged, verified) ----------------

__global__ __launch_bounds__(1024) void k_hist(const int* __restrict__ tgt,
                                               int* __restrict__ hist) {
    __shared__ int h[NB2];
    int w = blockIdx.x, t = threadIdx.x;
    for (int i = t; i < NB2; i += 1024) h[i] = 0;
    __syncthreads();
    int lo = w * CH, hi = min(lo + CH, NE);
    for (int e = lo + t; e < hi; e += 1024) atomicAdd(&h[tgt[e] >> BSH], 1);
    __syncthreads();
    for (int i = t; i < NB2; i += 1024) hist[w * NB2 + i] = h[i];
}

__global__ __launch_bounds__(512) void k_colscan(const int* __restrict__ hist,
                                                 int* __restrict__ loc,
                                                 int* __restrict__ bktot) {
    __shared__ int sd[512];
    int b = blockIdx.x, w = threadIdx.x;
    int v = hist[w * NB2 + b];
    sd[w] = v;
    __syncthreads();
    for (int off = 1; off < 512; off <<= 1) {
        int x = (w >= off) ? sd[w - off] : 0;
        __syncthreads();
        sd[w] += x;
        __syncthreads();
    }
    loc[b * NWG1 + w] = sd[w] - v;
    if (w == 511) bktot[b] = sd[511];
}

__global__ __launch_bounds__(512) void k_bktscan(const int* __restrict__ bktot,
                                                 int* __restrict__ bkbase) {
    __shared__ int sd[512];
    int t = threadIdx.x;
    int v = (t < NB2) ? bktot[t] : 0;
    sd[t] = v;
    __syncthreads();
    for (int off = 1; off < 512; off <<= 1) {
        int x = (t >= off) ? sd[t - off] : 0;
        __syncthreads();
        sd[t] += x;
        __syncthreads();
    }
    if (t < NB2) bkbase[t] = sd[t] - v;
    if (t == 0) bkbase[NB2] = NE;
}

__global__ __launch_bounds__(1024) void k_scatter(const int* __restrict__ ei,
                                                  const int* __restrict__ hist,
                                                  const int* __restrict__ loc,
                                                  const int* __restrict__ bkbase,
                                                  unsigned int* __restrict__ pair) {
    __shared__ int h[NB2], lc[NB2], adj[NB2];
    __shared__ int sc[512];
    __shared__ unsigned int stg[CH];
    __shared__ unsigned short stb[CH];
    int w = blockIdx.x, t = threadIdx.x;
    if (t < NB2) h[t] = hist[w * NB2 + t];
    if (t < 512) sc[t] = (t < NB2) ? hist[w * NB2 + t] : 0;
    __syncthreads();
    for (int off = 1; off < 512; off <<= 1) {
        int v = 0;
        if (t < 512 && t >= off) v = sc[t - off];
        __syncthreads();
        if (t < 512) sc[t] += v;
        __syncthreads();
    }
    if (t < NB2) {
        int lbase = sc[t] - h[t];
        lc[t] = lbase;
        adj[t] = loc[t * NWG1 + w] + bkbase[t] - lbase;
    }
    __syncthreads();
    int lo = w * CH, hi = min(lo + CH, NE);
    for (int e = lo + t; e < hi; e += 1024) {
        int s = ei[e], tg = ei[NE + e];
        int b = tg >> BSH;
        int lp = atomicAdd(&lc[b], 1);
        stg[lp] = ((unsigned int)s << BSH) | (unsigned int)(tg & (BW - 1));
        stb[lp] = (unsigned short)b;
    }
    __syncthreads();
    int n = hi - lo;
    for (int i = t; i < n; i += 1024) {
        pair[adj[stb[i]] + i] = stg[i];
    }
}

__global__ __launch_bounds__(1024) void k_bucketfill(const unsigned int* __restrict__ pair,
                                                     const int* __restrict__ bkbase,
                                                     int* __restrict__ rowptr,
                                                     float* __restrict__ dinv,
                                                     int* __restrict__ col) {
    __shared__ int nc[BW], sc[BW], cur[BW];
    __shared__ int colseg[CAP];
    int b = blockIdx.x, t = threadIdx.x;
    int lo = bkbase[b], hi = bkbase[b + 1];
    int cnt = hi - lo;
    if (t < BW) nc[t] = 0;
    __syncthreads();
    for (int e = lo + t; e < hi; e += 1024) atomicAdd(&nc[pair[e] & (BW - 1)], 1);
    __syncthreads();
    if (t < BW) sc[t] = nc[t];
    __syncthreads();
    for (int off = 1; off < BW; off <<= 1) {
        int v = 0;
        if (t < BW && t >= off) v = sc[t - off];
        __syncthreads();
        if (t < BW) sc[t] += v;
        __syncthreads();
    }
    if (t < BW) {
        int nofs = sc[t] - nc[t];
        cur[t] = nofs;
        int g = (b << BSH) + t;
        if (g < NN) {
            rowptr[g] = lo + nofs;
            dinv[g] = 1.0f / fmaxf((float)nc[t], 1.0f);
        }
    }
    if (b == NB2 - 1 && t == 0) rowptr[NN] = NE;
    __syncthreads();
    bool fast = (cnt <= CAP);
    for (int e = lo + t; e < hi; e += 1024) {
        unsigned int v = pair[e];
        int p = atomicAdd(&cur[v & (BW - 1)], 1);
        if (fast) colseg[p] = (int)(v >> BSH);
        else col[lo + p] = (int)(v >> BSH);
    }
    __syncthreads();
    if (fast) {
        for (int i = t; i < cnt; i += 1024) col[lo + i] = colseg[i];
    }
}

// ---------------- fp16 helpers ----------------

union H2U { __half2 h; unsigned int u; };

__device__ __forceinline__ void acc_half8(float* s, uint4 v) {
    H2U a, b, c, d;
    a.u = v.x; b.u = v.y; c.u = v.z; d.u = v.w;
    float2 f;
    f = __half22float2(a.h); s[0] += f.x; s[1] += f.y;
    f = __half22float2(b.h); s[2] += f.x; s[3] += f.y;
    f = __half22float2(c.h); s[4] += f.x; s[5] += f.y;
    f = __half22float2(d.h); s[6] += f.x; s[7] += f.y;
}

__device__ __forceinline__ void store_row16h(__half* p, const float* v) {
    unsigned int ua[8];
#pragma unroll
    for (int i = 0; i < 8; ++i) {
        H2U t;
        t.h = __floats2half2_rn(v[2 * i], v[2 * i + 1]);
        ua[i] = t.u;
    }
    uint4* pu = (uint4*)p;
    pu[0] = make_uint4(ua[0], ua[1], ua[2], ua[3]);
    pu[1] = make_uint4(ua[4], ua[5], ua[6], ua[7]);
}

// range-predicated gather of this lane's half of the edge list.
// PASS=0: sources < SPLIT; PASS=1: sources >= SPLIT. 3.2MB footprint per pass.
template <int PASS>
__device__ __forceinline__ void gather_pass(const __half* __restrict__ yin,
                                            const int* __restrict__ col,
                                            int beg, int end, int half, float* s) {
#pragma unroll
    for (int f = 0; f < 16; ++f) s[f] = 0.f;
    int j = beg + half;
    for (; j + 2 < end; j += 4) {
        int c0 = __ldg(&col[j]), c1 = __ldg(&col[j + 2]);
        bool p0 = PASS ? (c0 >= SPLIT) : (c0 < SPLIT);
        bool p1 = PASS ? (c1 >= SPLIT) : (c1 < SPLIT);
        if (p0) {
            const uint4* p = (const uint4*)(yin + (size_t)c0 * 16);
            uint4 a0 = p[0], a1 = p[1];
            acc_half8(s, a0); acc_half8(s + 8, a1);
        }
        if (p1) {
            const uint4* p = (const uint4*)(yin + (size_t)c1 * 16);
            uint4 a0 = p[0], a1 = p[1];
            acc_half8(s, a0); acc_half8(s + 8, a1);
        }
    }
    if (j < end) {
        int c = __ldg(&col[j]);
        bool pr = PASS ? (c >= SPLIT) : (c < SPLIT);
        if (pr) {
            const uint4* p = (const uint4*)(yin + (size_t)c * 16);
            uint4 a0 = p[0], a1 = p[1];
            acc_half8(s, a0); acc_half8(s + 8, a1);
        }
    }
}

// ---------------- pre-transformed GCN layers ----------------

// layer 1: gather x scalars (800KB, L2-fit: single pass), produce y2/z2.
__global__ __launch_bounds__(512, 6) void k_gcn1(
    const float* __restrict__ x, const int* __restrict__ rowptr,
    const int* __restrict__ col, const float* __restrict__ dinv,
    const float* __restrict__ Wr1, const float* __restrict__ b1,
    const float* __restrict__ Wl1, const float* __restrict__ Wr2,
    const float* __restrict__ b2, const float* __restrict__ Wl2,
    __half* __restrict__ y2, float* __restrict__ z2) {
    __shared__ float sWr1[20], sB1[20], sWl1[20];
    __shared__ float sWr2[15 * 20], sWl2[15 * 20], sB2[15];
    int t = threadIdx.x;
    if (t < 20) { sWr1[t] = Wr1[t]; sB1[t] = b1[t]; sWl1[t] = Wl1[t]; }
    for (int i = t; i < 300; i += 512) { sWr2[i] = Wr2[i]; sWl2[i] = Wl2[i]; }
    if (t < 15) sB2[t] = b2[t];
    __syncthreads();

    int n = blockIdx.x * 256 + (t >> 1);
    int half = t & 1;
    if (n >= NN) return;

    float xn = x[n];
    int beg = rowptr[n], end = rowptr[n + 1];
    float s = 0.f;
    int j = beg + half;
    for (; j + 2 < end; j += 4) {
        int c0 = __ldg(&col[j]), c1 = __ldg(&col[j + 2]);
        s += __ldg(&x[c0]) + __ldg(&x[c1]);
    }
    if (j < end) s += __ldg(&x[__ldg(&col[j])]);
    s += __shfl_xor(s, 1);

    if (half) return;
    float mean = s * dinv[n];
    float h1[20];
#pragma unroll
    for (int o = 0; o < 20; ++o)
        h1[o] = softplus_f(fmaf(mean, sWr1[o], fmaf(xn, sWl1[o], sB1[o])));

    float yo[16], zo[16];
#pragma unroll
    for (int o = 0; o < 15; ++o) {
        float ay = 0.f, az = 0.f;
#pragma unroll
        for (int f = 0; f < 20; ++f) {
            ay = fmaf(h1[f], sWr2[o * 20 + f], ay);
            az = fmaf(h1[f], sWl2[o * 20 + f], az);
        }
        yo[o] = ay;
        zo[o] = az + sB2[o];
    }
    yo[15] = 0.f; zo[15] = 0.f;
    store_row16h(y2 + (size_t)n * 16, yo);
    float4* pz = (float4*)(z2 + (size_t)n * 16);
#pragma unroll
    for (int i = 0; i < 4; ++i)
        pz[i] = make_float4(zo[4 * i], zo[4 * i + 1], zo[4 * i + 2], zo[4 * i + 3]);
}

// pass A: accumulate sources < SPLIT only; write partial sums (fp32).
__global__ __launch_bounds__(512, 6) void k_gA(const __half* __restrict__ yin,
                                               const int* __restrict__ rowptr,
                                               const int* __restrict__ col,
                                               float* __restrict__ spart) {
    int t = threadIdx.x;
    int n = blockIdx.x * 256 + (t >> 1);
    int half = t & 1;
    if (n >= NN) return;
    int beg = rowptr[n], end = rowptr[n + 1];
    float s[16];
    gather_pass<0>(yin, col, beg, end, half, s);
#pragma unroll
    for (int f = 0; f < 16; ++f) s[f] += __shfl_xor(s[f], 1);
    if (half) return;
    float4* ps = (float4*)(spart + (size_t)n * 16);
#pragma unroll
    for (int i = 0; i < 4; ++i)
        ps[i] = make_float4(s[4 * i], s[4 * i + 1], s[4 * i + 2], s[4 * i + 3]);
}

// pass B (middle layers): sources >= SPLIT, + spart, then epilogue -> y/z out.
template <int FO, int NFO>
__global__ __launch_bounds__(512, 6) void k_gB_T(
    const __half* __restrict__ yin, const float* __restrict__ spart,
    const float* __restrict__ zin, const int* __restrict__ rowptr,
    const int* __restrict__ col, const float* __restrict__ dinv,
    const float* __restrict__ WrN, const float* __restrict__ bN,
    const float* __restrict__ WlN,
    __half* __restrict__ yout, float* __restrict__ zout) {
    __shared__ float sWr[NFO * FO], sWl[NFO * FO], sB[NFO];
    for (int i = threadIdx.x; i < NFO * FO; i += 512) { sWr[i] = WrN[i]; sWl[i] = WlN[i]; }
    if (threadIdx.x < NFO) sB[threadIdx.x] = bN[threadIdx.x];
    __syncthreads();

    int t = threadIdx.x;
    int n = blockIdx.x * 256 + (t >> 1);
    int half = t & 1;
    if (n >= NN) return;
    int beg = rowptr[n], end = rowptr[n + 1];
    float s[16];
    gather_pass<1>(yin, col, beg, end, half, s);
#pragma unroll
    for (int f = 0; f < 16; ++f) s[f] += __shfl_xor(s[f], 1);
    if (half) return;

    const float4* ps = (const float4*)(spart + (size_t)n * 16);
#pragma unroll
    for (int i = 0; i < 4; ++i) {
        float4 v = ps[i];
        s[4 * i] += v.x; s[4 * i + 1] += v.y; s[4 * i + 2] += v.z; s[4 * i + 3] += v.w;
    }

    float di = dinv[n];
    const float4* pzr = (const float4*)(zin + (size_t)n * 16);
    float zr[16];
#pragma unroll
    for (int i = 0; i < 4; ++i) {
        float4 v = pzr[i];
        zr[4 * i] = v.x; zr[4 * i + 1] = v.y; zr[4 * i + 2] = v.z; zr[4 * i + 3] = v.w;
    }
    float h[FO];
#pragma unroll
    for (int f = 0; f < FO; ++f) h[f] = softplus_f(fmaf(s[f], di, zr[f]));

    float yo[16], zo[16];
#pragma unroll
    for (int o = 0; o < NFO; ++o) {
        float ay = 0.f, az = 0.f;
#pragma unroll
        for (int f = 0; f < FO; ++f) {
            ay = fmaf(h[f], sWr[o * FO + f], ay);
            az = fmaf(h[f], sWl[o * FO + f], az);
        }
        yo[o] = ay;
        zo[o] = az + sB[o];
    }
#pragma unroll
    for (int o = NFO; o < 16; ++o) { yo[o] = 0.f; zo[o] = 0.f; }
    store_row16h(yout + (size_t)n * 16, yo);
    float4* pz = (float4*)(zout + (size_t)n * 16);
#pragma unroll
    for (int i = 0; i < 4; ++i)
        pz[i] = make_float4(zo[4 * i], zo[4 * i + 1], zo[4 * i + 2], zo[4 * i + 3]);
}

// pass B (final layer): sources >= SPLIT, + spart, a0 = sp(s*di+z4), 4 FC layers.
__global__ __launch_bounds__(512, 6) void k_gB_fc(
    const __half* __restrict__ yin, const float* __restrict__ spart,
    const float* __restrict__ zin, const int* __restrict__ rowptr,
    const int* __restrict__ col, const float* __restrict__ dinv,
    const float* __restrict__ f1W, const float* __restrict__ f1b,
    const float* __restrict__ f2W, const float* __restrict__ f2b,
    const float* __restrict__ f3W, const float* __restrict__ f3b,
    const float* __restrict__ f4W, const float* __restrict__ f4b,
    float* __restrict__ out) {
    __shared__ float s1W[32 * 10], s1b[32];
    __shared__ float s2W[16 * 32], s2b[16];
    __shared__ float s3W[8 * 16], s3b[8];
    __shared__ float s4W[16 * 8], s4b[16];
    for (int i = threadIdx.x; i < 320; i += 512) s1W[i] = f1W[i];
    for (int i = threadIdx.x; i < 512; i += 512) s2W[i] = f2W[i];
    for (int i = threadIdx.x; i < 128; i += 512) s3W[i] = f3W[i];
    for (int i = threadIdx.x; i < 128; i += 512) s4W[i] = f4W[i];
    if (threadIdx.x < 32) s1b[threadIdx.x] = f1b[threadIdx.x];
    if (threadIdx.x < 16) s2b[threadIdx.x] = f2b[threadIdx.x];
    if (threadIdx.x < 8) s3b[threadIdx.x] = f3b[threadIdx.x];
    if (threadIdx.x < 16) s4b[threadIdx.x] = f4b[threadIdx.x];
    __syncthreads();

    int t = threadIdx.x;
    int n = blockIdx.x * 256 + (t >> 1);
    int half = t & 1;
    if (n >= NN) return;
    int beg = rowptr[n], end = rowptr[n + 1];
    float s[16];
    gather_pass<1>(yin, col, beg, end, half, s);
#pragma unroll
    for (int f = 0; f < 16; ++f) s[f] += __shfl_xor(s[f], 1);
    if (half) return;

    const float4* ps = (const float4*)(spart + (size_t)n * 16);
#pragma unroll
    for (int i = 0; i < 4; ++i) {
        float4 v = ps[i];
        s[4 * i] += v.x; s[4 * i + 1] += v.y; s[4 * i + 2] += v.z; s[4 * i + 3] += v.w;
    }

    float di = dinv[n];
    const float4* pzr = (const float4*)(zin + (size_t)n * 16);
    float zr[16];
#pragma unroll
    for (int i = 0; i < 4; ++i) {
        float4 v = pzr[i];
        zr[4 * i] = v.x; zr[4 * i + 1] = v.y; zr[4 * i + 2] = v.z; zr[4 * i + 3] = v.w;
    }
    float a0[10];
#pragma unroll
    for (int f = 0; f < 10; ++f) a0[f] = softplus_f(fmaf(s[f], di, zr[f]));

    float a1[32];
#pragma unroll
    for (int o = 0; o < 32; ++o) {
        float acc = s1b[o];
#pragma unroll
        for (int f = 0; f < 10; ++f) acc = fmaf(a0[f], s1W[o * 10 + f], acc);
        a1[o] = softplus_f(acc);
    }
    float a2[16];
#pragma unroll
    for (int o = 0; o < 16; ++o) {
        float acc = s2b[o];
#pragma unroll
        for (int f = 0; f < 32; ++f) acc = fmaf(a1[f], s2W[o * 32 + f], acc);
        a2[o] = softplus_f(acc);
    }
    float a3[8];
#pragma unroll
    for (int o = 0; o < 8; ++o) {
        float acc = s3b[o];
#pragma unroll
        for (int f = 0; f < 16; ++f) acc = fmaf(a2[f], s3W[o * 16 + f], acc);
        a3[o] = softplus_f(acc);
    }
    float a4[16];
#pragma unroll
    for (int o = 0; o < 16; ++o) {
        float acc = s4b[o];
#pragma unroll
        for (int f = 0; f < 8; ++f) acc = fmaf(a3[f], s4W[o * 8 + f], acc);
        a4[o] = acc;
    }
    float4* po = (float4*)(out + (size_t)n * 16);
#pragma unroll
    for (int i = 0; i < 4; ++i)
        po[i] = make_float4(a4[4 * i], a4[4 * i + 1], a4[4 * i + 2], a4[4 * i + 3]);
}

// ---------------- launch ----------------

extern "C" void kernel_launch(void* const* d_in, const int* in_sizes, int n_in,
                              void* d_out, int out_size, void* d_ws, size_t ws_size,
                              hipStream_t stream) {
    const float* x = (const float*)d_in[0];
    const int* ei = (const int*)d_in[1];  // int32 (harness converts integer inputs)
    const float* g1Wr = (const float*)d_in[2];
    const float* g1b = (const float*)d_in[3];
    const float* g1Wl = (const float*)d_in[4];
    const float* g2Wr = (const float*)d_in[5];
    const float* g2b = (const float*)d_in[6];
    const float* g2Wl = (const float*)d_in[7];
    const float* g3Wr = (const float*)d_in[8];
    const float* g3b = (const float*)d_in[9];
    const float* g3Wl = (const float*)d_in[10];
    const float* g4Wr = (const float*)d_in[11];
    const float* g4b = (const float*)d_in[12];
    const float* g4Wl = (const float*)d_in[13];
    const float* f1W = (const float*)d_in[14];
    const float* f1b = (const float*)d_in[15];
    const float* f2W = (const float*)d_in[16];
    const float* f2b = (const float*)d_in[17];
    const float* f3W = (const float*)d_in[18];
    const float* f3b = (const float*)d_in[19];
    const float* f4W = (const float*)d_in[20];
    const float* f4b = (const float*)d_in[21];
    float* out = (float*)d_out;

    char* ws = (char*)d_ws;
    size_t off = 0;
    auto alloc = [&](size_t bytes) {
        void* p = ws + off;
        off = (off + bytes + 255) & ~(size_t)255;
        return p;
    };
    int* hist = (int*)alloc((size_t)NWG1 * NB2 * 4);
    int* loc = (int*)alloc((size_t)NB2 * NWG1 * 4);
    int* bktot = (int*)alloc((size_t)NB2 * 4);
    int* bkbase = (int*)alloc((size_t)(NB2 + 1) * 4);
    unsigned int* pair = (unsigned int*)alloc((size_t)NE * 4);  // 16 MB; reused below
    int* rowptr = (int*)alloc((size_t)(NN + 1) * 4);
    float* dinv = (float*)alloc((size_t)NN * 4);
    int* col = (int*)alloc((size_t)NE * 4);
    float* z2 = (float*)alloc((size_t)NN * 16 * 4);
    __half* y3 = (__half*)alloc((size_t)NN * 16 * 2);
    float* z3 = (float*)alloc((size_t)NN * 16 * 4);
    float* spart = (float*)alloc((size_t)NN * 16 * 4);  // 12.8MB pass-A partials
    // region reuse (stream-ordered, lifetimes disjoint):
    __half* y2 = (__half*)pair;  // pair dead after k_bucketfill; y2 = 6.4 MB <= 16 MB
    __half* y4 = (__half*)pair;  // y2 dead after k_gB_T<15,12>
    float* z4 = z2;              // z2 dead after k_gB_T<15,12>

    // ---- binned CSR build ----
    k_hist<<<NWG1, 1024, 0, stream>>>(ei + NE, hist);
    k_colscan<<<NB2, 512, 0, stream>>>(hist, loc, bktot);
    k_bktscan<<<1, 512, 0, stream>>>(bktot, bkbase);
    k_scatter<<<NWG1, 1024, 0, stream>>>(ei, hist, loc, bkbase, pair);
    k_bucketfill<<<NB2, 1024, 0, stream>>>(pair, bkbase, rowptr, dinv, col);

    // ---- layers: 2-pass src-range blocking (3.2MB gather footprint per pass) ----
    const int GB = (NN + 255) / 256;
    k_gcn1<<<GB, 512, 0, stream>>>(x, rowptr, col, dinv, g1Wr, g1b, g1Wl, g2Wr, g2b, g2Wl,
                                   y2, z2);
    k_gA<<<GB, 512, 0, stream>>>(y2, rowptr, col, spart);
    k_gB_T<15, 12><<<GB, 512, 0, stream>>>(y2, spart, z2, rowptr, col, dinv, g3Wr, g3b,
                                           g3Wl, y3, z3);
    k_gA<<<GB, 512, 0, stream>>>(y3, rowptr, col, spart);
    k_gB_T<12, 10><<<GB, 512, 0, stream>>>(y3, spart, z3, rowptr, col, dinv, g4Wr, g4b,
                                           g4Wl, y4, z4);
    k_gA<<<GB, 512, 0, stream>>>(y4, rowptr, col, spart);
    k_gB_fc<<<GB, 512, 0, stream>>>(y4, spart, z4, rowptr, col, dinv, f1W, f1b, f2W, f2b,
                                    f3W, f3b, f4W, f4b, out);
}

// Round 15
// 550.114 us; speedup vs baseline: 1.1771x; 1.1771x over previous
//
#include <hip/hip_runtime.h>

#define NN 200000
#define NE 4000000

// ---- binned CSR build params ----
constexpr int BSH = 9;
constexpr int BW = 1 << BSH;                  // 512
constexpr int NB2 = (NN + BW - 1) / BW;       // 391
constexpr int NWG1 = 512;
constexpr int CH = (NE + NWG1 - 1) / NWG1;    // 7813
constexpr int CAP = 12288;
static_assert(NWG1 == 512, "shifts below assume 512");

__device__ __forceinline__ float softplus_f(float x) {
    return fmaxf(x, 0.0f) + log1pf(expf(-fabsf(x)));
}

// ---------------- binned CSR build (unchanged, verified) ----------------

__global__ __launch_bounds__(1024) void k_hist(const int* __restrict__ tgt,
                                               int* __restrict__ hist) {
    __shared__ int h[NB2];
    int w = blockIdx.x, t = threadIdx.x;
    for (int i = t; i < NB2; i += 1024) h[i] = 0;
    __syncthreads();
    int lo = w * CH, hi = min(lo + CH, NE);
    for (int e = lo + t; e < hi; e += 1024) atomicAdd(&h[tgt[e] >> BSH], 1);
    __syncthreads();
    for (int i = t; i < NB2; i += 1024) hist[w * NB2 + i] = h[i];
}

__global__ __launch_bounds__(512) void k_colscan(const int* __restrict__ hist,
                                                 int* __restrict__ loc,
                                                 int* __restrict__ bktot) {
    __shared__ int sd[512];
    int b = blockIdx.x, w = threadIdx.x;
    int v = hist[w * NB2 + b];
    sd[w] = v;
    __syncthreads();
    for (int off = 1; off < 512; off <<= 1) {
        int x = (w >= off) ? sd[w - off] : 0;
        __syncthreads();
        sd[w] += x;
        __syncthreads();
    }
    loc[b * NWG1 + w] = sd[w] - v;
    if (w == 511) bktot[b] = sd[511];
}

__global__ __launch_bounds__(512) void k_bktscan(const int* __restrict__ bktot,
                                                 int* __restrict__ bkbase) {
    __shared__ int sd[512];
    int t = threadIdx.x;
    int v = (t < NB2) ? bktot[t] : 0;
    sd[t] = v;
    __syncthreads();
    for (int off = 1; off < 512; off <<= 1) {
        int x = (t >= off) ? sd[t - off] : 0;
        __syncthreads();
        sd[t] += x;
        __syncthreads();
    }
    if (t < NB2) bkbase[t] = sd[t] - v;
    if (t == 0) bkbase[NB2] = NE;
}

__global__ __launch_bounds__(1024) void k_scatter(const int* __restrict__ ei,
                                                  const int* __restrict__ hist,
                                                  const int* __restrict__ loc,
                                                  const int* __restrict__ bkbase,
                                                  unsigned int* __restrict__ pair) {
    __shared__ int h[NB2], lc[NB2], adj[NB2];
    __shared__ int sc[512];
    __shared__ unsigned int stg[CH];
    __shared__ unsigned short stb[CH];
    int w = blockIdx.x, t = threadIdx.x;
    if (t < NB2) h[t] = hist[w * NB2 + t];
    if (t < 512) sc[t] = (t < NB2) ? hist[w * NB2 + t] : 0;
    __syncthreads();
    for (int off = 1; off < 512; off <<= 1) {
        int v = 0;
        if (t < 512 && t >= off) v = sc[t - off];
        __syncthreads();
        if (t < 512) sc[t] += v;
        __syncthreads();
    }
    if (t < NB2) {
        int lbase = sc[t] - h[t];
        lc[t] = lbase;
        adj[t] = loc[t * NWG1 + w] + bkbase[t] - lbase;
    }
    __syncthreads();
    int lo = w * CH, hi = min(lo + CH, NE);
    for (int e = lo + t; e < hi; e += 1024) {
        int s = ei[e], tg = ei[NE + e];
        int b = tg >> BSH;
        int lp = atomicAdd(&lc[b], 1);
        stg[lp] = ((unsigned int)s << BSH) | (unsigned int)(tg & (BW - 1));
        stb[lp] = (unsigned short)b;
    }
    __syncthreads();
    int n = hi - lo;
    for (int i = t; i < n; i += 1024) {
        pair[adj[stb[i]] + i] = stg[i];
    }
}

__global__ __launch_bounds__(1024) void k_bucketfill(const unsigned int* __restrict__ pair,
                                                     const int* __restrict__ bkbase,
                                                     int* __restrict__ rowptr,
                                                     float* __restrict__ dinv,
                                                     int* __restrict__ col) {
    __shared__ int nc[BW], sc[BW], cur[BW];
    __shared__ int colseg[CAP];
    int b = blockIdx.x, t = threadIdx.x;
    int lo = bkbase[b], hi = bkbase[b + 1];
    int cnt = hi - lo;
    if (t < BW) nc[t] = 0;
    __syncthreads();
    for (int e = lo + t; e < hi; e += 1024) atomicAdd(&nc[pair[e] & (BW - 1)], 1);
    __syncthreads();
    if (t < BW) sc[t] = nc[t];
    __syncthreads();
    for (int off = 1; off < BW; off <<= 1) {
        int v = 0;
        if (t < BW && t >= off) v = sc[t - off];
        __syncthreads();
        if (t < BW) sc[t] += v;
        __syncthreads();
    }
    if (t < BW) {
        int nofs = sc[t] - nc[t];
        cur[t] = nofs;
        int g = (b << BSH) + t;
        if (g < NN) {
            rowptr[g] = lo + nofs;
            dinv[g] = 1.0f / fmaxf((float)nc[t], 1.0f);
        }
    }
    if (b == NB2 - 1 && t == 0) rowptr[NN] = NE;
    __syncthreads();
    bool fast = (cnt <= CAP);
    for (int e = lo + t; e < hi; e += 1024) {
        unsigned int v = pair[e];
        int p = atomicAdd(&cur[v & (BW - 1)], 1);
        if (fast) colseg[p] = (int)(v >> BSH);
        else col[lo + p] = (int)(v >> BSH);
    }
    __syncthreads();
    if (fast) {
        for (int i = t; i < cnt; i += 1024) col[lo + i] = colseg[i];
    }
}

// ---------------- pre-transformed GCN layers ----------------
// Linearity: segsum(h[src]) @ Wr.T == segsum((h @ Wr.T)[src]). Each layer's
// epilogue computes y_next = h @ WrN.T (padded to 16 floats = one 64B line)
// and z_next = h @ WlN.T + bN densely; the next gather sums y rows only.

// layer 1: gather x scalars (L2-resident), produce y2/z2 for layer 2.
__global__ __launch_bounds__(512, 6) void k_gcn1(
    const float* __restrict__ x, const int* __restrict__ rowptr,
    const int* __restrict__ col, const float* __restrict__ dinv,
    const float* __restrict__ Wr1, const float* __restrict__ b1,
    const float* __restrict__ Wl1, const float* __restrict__ Wr2,
    const float* __restrict__ b2, const float* __restrict__ Wl2,
    float* __restrict__ y2, float* __restrict__ z2) {
    __shared__ float sWr1[20], sB1[20], sWl1[20];
    __shared__ float sWr2[15 * 20], sWl2[15 * 20], sB2[15];
    int t = threadIdx.x;
    if (t < 20) { sWr1[t] = Wr1[t]; sB1[t] = b1[t]; sWl1[t] = Wl1[t]; }
    for (int i = t; i < 300; i += 512) { sWr2[i] = Wr2[i]; sWl2[i] = Wl2[i]; }
    if (t < 15) sB2[t] = b2[t];
    __syncthreads();

    int n = blockIdx.x * 256 + (t >> 1);
    int half = t & 1;
    if (n >= NN) return;

    float xn = x[n];
    int beg = rowptr[n], end = rowptr[n + 1];
    float s = 0.f;
    int j = beg + half;
    for (; j + 2 < end; j += 4) {
        int c0 = __ldg(&col[j]), c1 = __ldg(&col[j + 2]);
        s += __ldg(&x[c0]) + __ldg(&x[c1]);
    }
    if (j < end) s += __ldg(&x[__ldg(&col[j])]);
    s += __shfl_xor(s, 1);

    if (half) return;
    float mean = s * dinv[n];
    float h1[20];
#pragma unroll
    for (int o = 0; o < 20; ++o)
        h1[o] = softplus_f(fmaf(mean, sWr1[o], fmaf(xn, sWl1[o], sB1[o])));

    float yo[16], zo[16];
#pragma unroll
    for (int o = 0; o < 15; ++o) {
        float ay = 0.f, az = 0.f;
#pragma unroll
        for (int f = 0; f < 20; ++f) {
            ay = fmaf(h1[f], sWr2[o * 20 + f], ay);
            az = fmaf(h1[f], sWl2[o * 20 + f], az);
        }
        yo[o] = ay;
        zo[o] = az + sB2[o];
    }
    yo[15] = 0.f; zo[15] = 0.f;
    float4* py = (float4*)(y2 + (size_t)n * 16);
    float4* pz = (float4*)(z2 + (size_t)n * 16);
#pragma unroll
    for (int i = 0; i < 4; ++i) {
        py[i] = make_float4(yo[4 * i], yo[4 * i + 1], yo[4 * i + 2], yo[4 * i + 3]);
        pz[i] = make_float4(zo[4 * i], zo[4 * i + 1], zo[4 * i + 2], zo[4 * i + 3]);
    }
}

// middle layers: gather one 64B y row per edge; h = sp(s*di + z); emit next y/z.
template <int FO, int NFO>
__global__ __launch_bounds__(512, 6) void k_gcnT(
    const float* __restrict__ yin, const float* __restrict__ zin,
    const int* __restrict__ rowptr, const int* __restrict__ col,
    const float* __restrict__ dinv, const float* __restrict__ WrN,
    const float* __restrict__ bN, const float* __restrict__ WlN,
    float* __restrict__ yout, float* __restrict__ zout) {
    __shared__ float sWr[NFO * FO], sWl[NFO * FO], sB[NFO];
    for (int i = threadIdx.x; i < NFO * FO; i += 512) { sWr[i] = WrN[i]; sWl[i] = WlN[i]; }
    if (threadIdx.x < NFO) sB[threadIdx.x] = bN[threadIdx.x];
    __syncthreads();

    int t = threadIdx.x;
    int n = blockIdx.x * 256 + (t >> 1);
    int half = t & 1;
    if (n >= NN) return;

    float s[16];
#pragma unroll
    for (int f = 0; f < 16; ++f) s[f] = 0.f;
    int beg = rowptr[n], end = rowptr[n + 1];
    int j = beg + half;
    for (; j + 2 < end; j += 4) {
        int c0 = __ldg(&col[j]), c1 = __ldg(&col[j + 2]);
        const float4* p0 = (const float4*)(yin + (size_t)c0 * 16);
        const float4* p1 = (const float4*)(yin + (size_t)c1 * 16);
        float4 v0[4], v1[4];
#pragma unroll
        for (int i = 0; i < 4; ++i) { v0[i] = p0[i]; v1[i] = p1[i]; }
#pragma unroll
        for (int i = 0; i < 4; ++i) {
            s[4 * i + 0] += v0[i].x + v1[i].x;
            s[4 * i + 1] += v0[i].y + v1[i].y;
            s[4 * i + 2] += v0[i].z + v1[i].z;
            s[4 * i + 3] += v0[i].w + v1[i].w;
        }
    }
    if (j < end) {
        const float4* p0 = (const float4*)(yin + (size_t)__ldg(&col[j]) * 16);
#pragma unroll
        for (int i = 0; i < 4; ++i) {
            float4 v = p0[i];
            s[4 * i + 0] += v.x; s[4 * i + 1] += v.y;
            s[4 * i + 2] += v.z; s[4 * i + 3] += v.w;
        }
    }
#pragma unroll
    for (int f = 0; f < 16; ++f) s[f] += __shfl_xor(s[f], 1);

    if (half) return;
    float di = dinv[n];
    const float4* pzr = (const float4*)(zin + (size_t)n * 16);
    float zr[16];
#pragma unroll
    for (int i = 0; i < 4; ++i) {
        float4 v = pzr[i];
        zr[4 * i] = v.x; zr[4 * i + 1] = v.y; zr[4 * i + 2] = v.z; zr[4 * i + 3] = v.w;
    }
    float h[FO];
#pragma unroll
    for (int f = 0; f < FO; ++f) h[f] = softplus_f(fmaf(s[f], di, zr[f]));

    float yo[16], zo[16];
#pragma unroll
    for (int o = 0; o < NFO; ++o) {
        float ay = 0.f, az = 0.f;
#pragma unroll
        for (int f = 0; f < FO; ++f) {
            ay = fmaf(h[f], sWr[o * FO + f], ay);
            az = fmaf(h[f], sWl[o * FO + f], az);
        }
        yo[o] = ay;
        zo[o] = az + sB[o];
    }
#pragma unroll
    for (int o = NFO; o < 16; ++o) { yo[o] = 0.f; zo[o] = 0.f; }
    float4* py = (float4*)(yout + (size_t)n * 16);
    float4* pz = (float4*)(zout + (size_t)n * 16);
#pragma unroll
    for (int i = 0; i < 4; ++i) {
        py[i] = make_float4(yo[4 * i], yo[4 * i + 1], yo[4 * i + 2], yo[4 * i + 3]);
        pz[i] = make_float4(zo[4 * i], zo[4 * i + 1], zo[4 * i + 2], zo[4 * i + 3]);
    }
}

// final layer: gather y4 (1 line), a0 = sp(s*di + z4), then the 4 FC layers.
__global__ __launch_bounds__(512, 6) void k_gcn4_fc(
    const float* __restrict__ yin, const float* __restrict__ zin,
    const int* __restrict__ rowptr, const int* __restrict__ col,
    const float* __restrict__ dinv,
    const float* __restrict__ f1W, const float* __restrict__ f1b,
    const float* __restrict__ f2W, const float* __restrict__ f2b,
    const float* __restrict__ f3W, const float* __restrict__ f3b,
    const float* __restrict__ f4W, const float* __restrict__ f4b,
    float* __restrict__ out) {
    __shared__ float s1W[32 * 10], s1b[32];
    __shared__ float s2W[16 * 32], s2b[16];
    __shared__ float s3W[8 * 16], s3b[8];
    __shared__ float s4W[16 * 8], s4b[16];
    for (int i = threadIdx.x; i < 320; i += 512) s1W[i] = f1W[i];
    for (int i = threadIdx.x; i < 512; i += 512) s2W[i] = f2W[i];
    for (int i = threadIdx.x; i < 128; i += 512) s3W[i] = f3W[i];
    for (int i = threadIdx.x; i < 128; i += 512) s4W[i] = f4W[i];
    if (threadIdx.x < 32) s1b[threadIdx.x] = f1b[threadIdx.x];
    if (threadIdx.x < 16) s2b[threadIdx.x] = f2b[threadIdx.x];
    if (threadIdx.x < 8) s3b[threadIdx.x] = f3b[threadIdx.x];
    if (threadIdx.x < 16) s4b[threadIdx.x] = f4b[threadIdx.x];
    __syncthreads();

    int t = threadIdx.x;
    int n = blockIdx.x * 256 + (t >> 1);
    int half = t & 1;
    if (n >= NN) return;

    float s[16];
#pragma unroll
    for (int f = 0; f < 16; ++f) s[f] = 0.f;
    int beg = rowptr[n], end = rowptr[n + 1];
    int j = beg + half;
    for (; j + 2 < end; j += 4) {
        int c0 = __ldg(&col[j]), c1 = __ldg(&col[j + 2]);
        const float4* p0 = (const float4*)(yin + (size_t)c0 * 16);
        const float4* p1 = (const float4*)(yin + (size_t)c1 * 16);
        float4 v0[4], v1[4];
#pragma unroll
        for (int i = 0; i < 4; ++i) { v0[i] = p0[i]; v1[i] = p1[i]; }
#pragma unroll
        for (int i = 0; i < 4; ++i) {
            s[4 * i + 0] += v0[i].x + v1[i].x;
            s[4 * i + 1] += v0[i].y + v1[i].y;
            s[4 * i + 2] += v0[i].z + v1[i].z;
            s[4 * i + 3] += v0[i].w + v1[i].w;
        }
    }
    if (j < end) {
        const float4* p0 = (const float4*)(yin + (size_t)__ldg(&col[j]) * 16);
#pragma unroll
        for (int i = 0; i < 4; ++i) {
            float4 v = p0[i];
            s[4 * i + 0] += v.x; s[4 * i + 1] += v.y;
            s[4 * i + 2] += v.z; s[4 * i + 3] += v.w;
        }
    }
#pragma unroll
    for (int f = 0; f < 16; ++f) s[f] += __shfl_xor(s[f], 1);

    if (half) return;
    float di = dinv[n];
    const float4* pzr = (const float4*)(zin + (size_t)n * 16);
    float zr[16];
#pragma unroll
    for (int i = 0; i < 4; ++i) {
        float4 v = pzr[i];
        zr[4 * i] = v.x; zr[4 * i + 1] = v.y; zr[4 * i + 2] = v.z; zr[4 * i + 3] = v.w;
    }
    float a0[10];
#pragma unroll
    for (int f = 0; f < 10; ++f) a0[f] = softplus_f(fmaf(s[f], di, zr[f]));

    float a1[32];
#pragma unroll
    for (int o = 0; o < 32; ++o) {
        float acc = s1b[o];
#pragma unroll
        for (int f = 0; f < 10; ++f) acc = fmaf(a0[f], s1W[o * 10 + f], acc);
        a1[o] = softplus_f(acc);
    }
    float a2[16];
#pragma unroll
    for (int o = 0; o < 16; ++o) {
        float acc = s2b[o];
#pragma unroll
        for (int f = 0; f < 32; ++f) acc = fmaf(a1[f], s2W[o * 32 + f], acc);
        a2[o] = softplus_f(acc);
    }
    float a3[8];
#pragma unroll
    for (int o = 0; o < 8; ++o) {
        float acc = s3b[o];
#pragma unroll
        for (int f = 0; f < 16; ++f) acc = fmaf(a2[f], s3W[o * 16 + f], acc);
        a3[o] = softplus_f(acc);
    }
    float a4[16];
#pragma unroll
    for (int o = 0; o < 16; ++o) {
        float acc = s4b[o];
#pragma unroll
        for (int f = 0; f < 8; ++f) acc = fmaf(a3[f], s4W[o * 8 + f], acc);
        a4[o] = acc;
    }
    float4* po = (float4*)(out + (size_t)n * 16);
#pragma unroll
    for (int i = 0; i < 4; ++i)
        po[i] = make_float4(a4[4 * i], a4[4 * i + 1], a4[4 * i + 2], a4[4 * i + 3]);
}

// ---------------- launch ----------------

extern "C" void kernel_launch(void* const* d_in, const int* in_sizes, int n_in,
                              void* d_out, int out_size, void* d_ws, size_t ws_size,
                              hipStream_t stream) {
    const float* x = (const float*)d_in[0];
    const int* ei = (const int*)d_in[1];  // int32 (harness converts integer inputs)
    const float* g1Wr = (const float*)d_in[2];
    const float* g1b = (const float*)d_in[3];
    const float* g1Wl = (const float*)d_in[4];
    const float* g2Wr = (const float*)d_in[5];
    const float* g2b = (const float*)d_in[6];
    const float* g2Wl = (const float*)d_in[7];
    const float* g3Wr = (const float*)d_in[8];
    const float* g3b = (const float*)d_in[9];
    const float* g3Wl = (const float*)d_in[10];
    const float* g4Wr = (const float*)d_in[11];
    const float* g4b = (const float*)d_in[12];
    const float* g4Wl = (const float*)d_in[13];
    const float* f1W = (const float*)d_in[14];
    const float* f1b = (const float*)d_in[15];
    const float* f2W = (const float*)d_in[16];
    const float* f2b = (const float*)d_in[17];
    const float* f3W = (const float*)d_in[18];
    const float* f3b = (const float*)d_in[19];
    const float* f4W = (const float*)d_in[20];
    const float* f4b = (const float*)d_in[21];
    float* out = (float*)d_out;

    char* ws = (char*)d_ws;
    size_t off = 0;
    auto alloc = [&](size_t bytes) {
        void* p = ws + off;
        off = (off + bytes + 255) & ~(size_t)255;
        return p;
    };
    int* hist = (int*)alloc((size_t)NWG1 * NB2 * 4);
    int* loc = (int*)alloc((size_t)NB2 * NWG1 * 4);
    int* bktot = (int*)alloc((size_t)NB2 * 4);
    int* bkbase = (int*)alloc((size_t)(NB2 + 1) * 4);
    unsigned int* pair = (unsigned int*)alloc((size_t)NE * 4);  // 16 MB; reused below
    int* rowptr = (int*)alloc((size_t)(NN + 1) * 4);
    float* dinv = (float*)alloc((size_t)NN * 4);
    int* col = (int*)alloc((size_t)NE * 4);
    float* z2 = (float*)alloc((size_t)NN * 16 * 4);
    float* y3 = (float*)alloc((size_t)NN * 16 * 4);
    float* z3 = (float*)alloc((size_t)NN * 16 * 4);
    // region reuse (stream-ordered, lifetimes disjoint):
    float* y2 = (float*)pair;  // pair dead after k_bucketfill; y2 = 12.8 MB <= 16 MB
    float* y4 = (float*)pair;  // y2 dead after k_gcnT<15,12>
    float* z4 = z2;            // z2 dead after k_gcnT<15,12>

    // ---- binned CSR build ----
    k_hist<<<NWG1, 1024, 0, stream>>>(ei + NE, hist);
    k_colscan<<<NB2, 512, 0, stream>>>(hist, loc, bktot);
    k_bktscan<<<1, 512, 0, stream>>>(bktot, bkbase);
    k_scatter<<<NWG1, 1024, 0, stream>>>(ei, hist, loc, bkbase, pair);
    k_bucketfill<<<NB2, 1024, 0, stream>>>(pair, bkbase, rowptr, dinv, col);

    // ---- layers (pre-transformed; every gather = one aligned 64B line) ----
    const int GB = (NN + 255) / 256;
    k_gcn1<<<GB, 512, 0, stream>>>(x, rowptr, col, dinv, g1Wr, g1b, g1Wl, g2Wr, g2b, g2Wl,
                                   y2, z2);
    k_gcnT<15, 12><<<GB, 512, 0, stream>>>(y2, z2, rowptr, col, dinv, g3Wr, g3b, g3Wl,
                                           y3, z3);
    k_gcnT<12, 10><<<GB, 512, 0, stream>>>(y3, z3, rowptr, col, dinv, g4Wr, g4b, g4Wl,
                                           y4, z4);
    k_gcn4_fc<<<GB, 512, 0, stream>>>(y4, z4, rowptr, col, dinv, f1W, f1b, f2W, f2b, f3W,
                                      f3b, f4W, f4b, out);
}